// Round 1
// baseline (558.490 us; speedup 1.0000x reference)
//
#include <hip/hip_runtime.h>
#include <hip/hip_bf16.h>
#include <stdint.h>

#define D_IN  4096
#define D_OUT 4096
#define MROWS 8192   // 2 * 4096 rows of x

using bf16x8 = __attribute__((ext_vector_type(8))) short;
using f32x4  = __attribute__((ext_vector_type(4))) float;

__device__ __forceinline__ unsigned short f2bf(float f) {
  union { float f; unsigned u; } a; a.f = f;
  // round-to-nearest-even fp32 -> bf16 (no NaN handling needed here)
  return (unsigned short)((a.u + 0x7FFFu + ((a.u >> 16) & 1u)) >> 16);
}

// ---------------- Kernel 1: RMSNorm (fp32 math) -> bf16 xn ----------------
__global__ __launch_bounds__(256) void rmsnorm_kernel(
    const float* __restrict__ x, const float* __restrict__ nw,
    unsigned short* __restrict__ xn) {
  const int row = blockIdx.x;
  const int t = threadIdx.x;
  const float4* xr  = (const float4*)(x + (size_t)row * D_IN);
  const float4* nw4 = (const float4*)nw;

  float4 v[4];
  float ss = 0.f;
#pragma unroll
  for (int i = 0; i < 4; ++i) {
    v[i] = xr[i * 256 + t];
    ss += v[i].x * v[i].x + v[i].y * v[i].y + v[i].z * v[i].z + v[i].w * v[i].w;
  }
#pragma unroll
  for (int off = 32; off > 0; off >>= 1) ss += __shfl_down(ss, off, 64);

  __shared__ float red[4];
  if ((t & 63) == 0) red[t >> 6] = ss;
  __syncthreads();
  const float scale =
      rsqrtf((red[0] + red[1] + red[2] + red[3]) * (1.0f / D_IN) + 1e-6f);

  ushort4* out = (ushort4*)(xn + (size_t)row * D_IN);
#pragma unroll
  for (int i = 0; i < 4; ++i) {
    const float4 w = nw4[i * 256 + t];
    ushort4 o;
    o.x = f2bf(v[i].x * scale * w.x);
    o.y = f2bf(v[i].y * scale * w.y);
    o.z = f2bf(v[i].z * scale * w.z);
    o.w = f2bf(v[i].w * scale * w.w);
    out[i * 256 + t] = o;
  }
}

// ---------------- Kernel 2: w_q fp32 -> bf16 (exact: values in {-1,0,1}) ---
__global__ __launch_bounds__(256) void cvt_kernel(
    const float* __restrict__ w, unsigned short* __restrict__ wb, int n4) {
  const int i = blockIdx.x * 256 + threadIdx.x;
  if (i >= n4) return;
  const float4 v = ((const float4*)w)[i];
  ushort4 o;
  o.x = f2bf(v.x); o.y = f2bf(v.y); o.z = f2bf(v.z); o.w = f2bf(v.w);
  ((ushort4*)wb)[i] = o;
}

// ---------------- Kernel 3: bf16 GEMM (A: MxK, B: NxK i.e. B^T), + gamma ---
#define BM 128
#define BN 128
#define BK 32

__global__ __launch_bounds__(256) void gemm_kernel(
    const unsigned short* __restrict__ A,   // MROWS x D_IN bf16
    const unsigned short* __restrict__ B,   // D_OUT x D_IN bf16 (N-major, K-contig)
    const float* __restrict__ gamma,        // D_OUT
    float* __restrict__ C) {                // MROWS x D_OUT fp32
  __shared__ short sA[BM * BK];  // 8 KB, row-major [128][32]
  __shared__ short sB[BN * BK];  // 8 KB

  const int tid  = threadIdx.x;
  const int lane = tid & 63;
  const int wv   = tid >> 6;
  const int wm   = wv & 1;        // 2x2 wave grid, each wave owns 64x64
  const int wn   = wv >> 1;
  const int bm   = blockIdx.y;
  const int bn   = blockIdx.x;

  f32x4 acc[4][4];
#pragma unroll
  for (int i = 0; i < 4; ++i)
#pragma unroll
    for (int j = 0; j < 4; ++j) acc[i][j] = (f32x4){0.f, 0.f, 0.f, 0.f};

  const size_t aBase = (size_t)(bm * BM) * D_IN;
  const size_t bBase = (size_t)(bn * BN) * D_IN;

  for (int k0 = 0; k0 < D_IN; k0 += BK) {
    // Stage A-tile and B-tile: 512 chunks of 16B each; 2 loads/thread/matrix.
    // LDS dest must be wave-uniform base + lane*16 (global_load_lds semantics).
#pragma unroll
    for (int i = 0; i < 2; ++i) {
      const int c = i * 256 + tid;        // chunk id
      const int r = c >> 2;               // tile row
      const int cc = (c & 3) * 8;         // k offset within tile
      __builtin_amdgcn_global_load_lds(
          (__attribute__((address_space(1))) void*)(A + aBase + (size_t)r * D_IN + k0 + cc),
          (__attribute__((address_space(3))) void*)&sA[(i * 256 + wv * 64) * 8],
          16, 0, 0);
    }
#pragma unroll
    for (int i = 0; i < 2; ++i) {
      const int c = i * 256 + tid;
      const int r = c >> 2;
      const int cc = (c & 3) * 8;
      __builtin_amdgcn_global_load_lds(
          (__attribute__((address_space(1))) void*)(B + bBase + (size_t)r * D_IN + k0 + cc),
          (__attribute__((address_space(3))) void*)&sB[(i * 256 + wv * 64) * 8],
          16, 0, 0);
    }
    __syncthreads();   // compiler emits s_waitcnt vmcnt(0) before s_barrier

    bf16x8 af[4], bfr[4];
    const int m0 = wm * 64 + (lane & 15);
    const int n0 = wn * 64 + (lane & 15);
    const int kk = (lane >> 4) * 8;       // A/B operand: [m|n = lane&15][k = quad*8+j]
#pragma unroll
    for (int i = 0; i < 4; ++i) af[i]  = *(const bf16x8*)&sA[(m0 + i * 16) * BK + kk];
#pragma unroll
    for (int j = 0; j < 4; ++j) bfr[j] = *(const bf16x8*)&sB[(n0 + j * 16) * BK + kk];

#pragma unroll
    for (int i = 0; i < 4; ++i)
#pragma unroll
      for (int j = 0; j < 4; ++j)
        acc[i][j] = __builtin_amdgcn_mfma_f32_16x16x32_bf16(af[i], bfr[j], acc[i][j], 0, 0, 0);

    __syncthreads();
  }

  // Epilogue: C/D layout col = lane&15, row = (lane>>4)*4 + reg. Fuse gamma.
  const int col0 = bn * BN + wn * 64 + (lane & 15);
  const int row0 = bm * BM + wm * 64 + ((lane >> 4) * 4);
#pragma unroll
  for (int j = 0; j < 4; ++j) {
    const float g = gamma[col0 + j * 16];
#pragma unroll
    for (int i = 0; i < 4; ++i) {
      const int rb = row0 + i * 16;
#pragma unroll
      for (int r = 0; r < 4; ++r) {
        C[(size_t)(rb + r) * D_OUT + (col0 + j * 16)] = acc[i][j][r] * g;
      }
    }
  }
}

extern "C" void kernel_launch(void* const* d_in, const int* in_sizes, int n_in,
                              void* d_out, int out_size, void* d_ws, size_t ws_size,
                              hipStream_t stream) {
  const float* x     = (const float*)d_in[0];  // (2,4096,4096)
  const float* nw    = (const float*)d_in[1];  // (4096,)
  const float* wq    = (const float*)d_in[2];  // (4096,4096) {-1,0,1}
  const float* gamma = (const float*)d_in[3];  // (4096,)
  float* y = (float*)d_out;

  // Workspace layout: xn bf16 (64 MB) | wq bf16 (32 MB)  => 96 MB total
  unsigned short* xn = (unsigned short*)d_ws;
  unsigned short* wb = xn + (size_t)MROWS * D_IN;

  rmsnorm_kernel<<<MROWS, 256, 0, stream>>>(x, nw, xn);

  const int n4 = (D_OUT * D_IN) / 4;
  cvt_kernel<<<(n4 + 255) / 256, 256, 0, stream>>>(wq, wb, n4);

  gemm_kernel<<<dim3(D_OUT / BN, MROWS / BM), 256, 0, stream>>>(xn, wb, gamma, y);
}